// Round 10
// baseline (159.736 us; speedup 1.0000x reference)
//
#include <hip/hip_runtime.h>

typedef __attribute__((ext_vector_type(4))) unsigned int u32x4;
typedef __attribute__((ext_vector_type(4))) int i32x4;

union I16 { u32x4 u; i32x4 i; };

#define SA_INV   (127.0f / 12.0f)           // a = -2z, |a| <= 12 (z tail ~5.2)
#define SB_INV   (127.0f * 8192.0f)         // b in [-1/8192, 1/8192]
#define INV_SASB ((127.0 * 127.0 * 8192.0) / 12.0)   // 1/(sa*sb) ~ 1.101e7
#define WI       4500                        // refine window in int units (~4e-4)
#define FINF     3.4e38f

__device__ __forceinline__ int q8(float x, float s) {
    int q = (int)__builtin_rintf(x * s);
    return q < -127 ? -127 : (q > 127 ? 127 : q);
}

// ---------------------------------------------------------------------------
// prep_all R17: identical to verified R14 except ibt is written TRANSPOSED:
// ibt_t[(code>>9)*512 + (code&15)*32 + ((code>>4)&31)] -- i.e.
// [stripe][colc][tile] -- so vq_main can load 4 tiles of ibt per dwordx4.
// Same value, same buffer size; pure layout change.
// ---------------------------------------------------------------------------
__global__ __launch_bounds__(256)
void prep_all(const float* __restrict__ z, const float* __restrict__ cb,
              u32x4* __restrict__ ahi, float* __restrict__ zt,
              float* __restrict__ z2f, float* __restrict__ c2,
              unsigned int* __restrict__ ibt, u32x4* __restrict__ bstr) {
    __shared__ double pzbuf[32 * 9];              // doubles / pc floats
    __shared__ float tile[32 * 257];
    int tid = threadIdx.x;
    if (blockIdx.x < 512) {
        // ---- codebook path: one 16-code tile per block ----
        float* t16 = tile;                        // [16][257]
        float* pc = (float*)pzbuf;                // [16][17]
        int ct = blockIdx.x;
        int cl = tid >> 4, dseg = tid & 15;
        const float* src = cb + (size_t)(ct * 16 + cl) * 256 + dseg * 16;
        float s = 0.f;
#pragma unroll
        for (int q = 0; q < 4; ++q) {             // 4 x float4 = 16 floats, in order
            float4 v = *reinterpret_cast<const float4*>(src + q * 4);
            t16[cl * 257 + dseg * 16 + q * 4 + 0] = v.x; s += v.x * v.x;
            t16[cl * 257 + dseg * 16 + q * 4 + 1] = v.y; s += v.y * v.y;
            t16[cl * 257 + dseg * 16 + q * 4 + 2] = v.z; s += v.z * v.z;
            t16[cl * 257 + dseg * 16 + q * 4 + 3] = v.w; s += v.w * v.w;
        }
        pc[cl * 17 + dseg] = s;
        __syncthreads();
        if (tid < 16) {
            float t = 0.f;
#pragma unroll
            for (int i = 0; i < 16; ++i) t += pc[tid * 17 + i];
            int code = ct * 16 + tid;
            c2[code] = t;
            int ib = (int)__builtin_rintf(t * (float)INV_SASB);
            unsigned int val = (((unsigned int)(ib + 262144)) << 6) | (unsigned int)((code >> 4) & 31);
            // transposed: [stripe][colc][tile]
            ibt[(ct >> 5) * 512 + tid * 32 + (ct & 31)] = val;
        }
        int l = tid & 63, j = tid >> 6;
        int code_l = l & 15, k0 = j * 64 + ((l >> 4) << 4);
        u32x4 v;
#pragma unroll
        for (int d = 0; d < 4; ++d) {
            unsigned int wv = 0;
#pragma unroll
            for (int bb = 0; bb < 4; ++bb) {
                int q = q8(t16[code_l * 257 + k0 + d * 4 + bb], SB_INV);
                wv |= ((unsigned int)(q & 255)) << (8 * bb);
            }
            v[d] = wv;
        }
        bstr[(size_t)(ct * 4 + j) * 64 + l] = v;
    } else {
        // ---- z path: one (b,h) pair per block ----
        int bh = blockIdx.x - 512;                // 0..511
        int b = bh >> 5, h = bh & 31;
        for (int e = tid; e < 2048; e += 256) {   // float4 over w
            int d = e >> 3, w4 = e & 7;
            float4 v = *reinterpret_cast<const float4*>(
                z + (((size_t)(b * 256 + d) * 32 + h) * 32) + w4 * 4);
            tile[(w4 * 4 + 0) * 257 + d] = v.x;
            tile[(w4 * 4 + 1) * 257 + d] = v.y;
            tile[(w4 * 4 + 2) * 257 + d] = v.z;
            tile[(w4 * 4 + 3) * 257 + d] = v.w;
        }
        __syncthreads();
        for (int e = tid; e < 2048; e += 256) {   // float4 over d
            int w = e >> 6, d4 = e & 63;
            float4 v;
            v.x = tile[w * 257 + d4 * 4 + 0];
            v.y = tile[w * 257 + d4 * 4 + 1];
            v.z = tile[w * 257 + d4 * 4 + 2];
            v.w = tile[w * 257 + d4 * 4 + 3];
            *reinterpret_cast<float4*>(zt + (size_t)(bh * 32 + w) * 256 + d4 * 4) = v;
        }
        {
            int w = tid >> 3, seg = tid & 7;
            double s = 0.0;
#pragma unroll
            for (int d = 0; d < 32; ++d) { double v = (double)tile[w * 257 + seg * 32 + d]; s += v * v; }
            pzbuf[w * 9 + seg] = s;
        }
        __syncthreads();
        if (tid < 32) {
            double s = 0.0;
#pragma unroll
            for (int seg = 0; seg < 8; ++seg) s += pzbuf[tid * 9 + seg];
            z2f[bh * 32 + tid] = (float)s;
        }
        for (int o = tid; o < 512; o += 256) {    // 2 row-tiles x 4 j x 64 lanes
            int l = o & 63, j = (o >> 6) & 3, tt = o >> 8;
            int wp = tt * 16 + (l & 15);
            int k0 = j * 64 + ((l >> 4) << 4);
            u32x4 v;
#pragma unroll
            for (int d = 0; d < 4; ++d) {
                unsigned int wv = 0;
#pragma unroll
                for (int bb = 0; bb < 4; ++bb) {
                    int q = q8(-2.0f * tile[wp * 257 + k0 + d * 4 + bb], SA_INV);
                    wv |= ((unsigned int)(q & 255)) << (8 * bb);
                }
                v[d] = wv;
            }
            ahi[(size_t)bh * 512 + o] = v;
        }
    }
}

// ---------------------------------------------------------------------------
// vq_main R17: R15 skeleton (verified 67.6 us: XCD remap, reg double-buffer,
// med3 top-2, top-3 tail) with ONE change: ibt loaded via dwordx4, 4 tiles
// per load, from the transposed layout (VMEM insts per 4 tiles: 20 -> 17,
// and removes a dependent scalar load from every 2-tile step). Loop is a
// 4-tile step so all vector indices are compile-time (no scratch). Prefetch
// distances identical to R15 (B-frag loaded one tilework ahead of use).
// ---------------------------------------------------------------------------
__global__ __launch_bounds__(256)
void vq_main(const u32x4* __restrict__ ahi4, const u32x4* __restrict__ bstr,
             const unsigned int* __restrict__ ibt_t,
             unsigned int* __restrict__ cd, int* __restrict__ ci) {
    int tid = threadIdx.x;
    int wid = tid >> 6, lane = tid & 63;
    int b = blockIdx.x;
    int stripe = (b >> 3) & 15;                   // v
    int rg = (b & 7) * 16 + (b >> 7);             // x*16 + u, 0..127
    int colc = lane & 15;
    int rt0 = rg * 8 + wid * 2;                   // wave's 2 row-tiles (32 rows)

    I16 ah[2][4];
#pragma unroll
    for (int rt = 0; rt < 2; ++rt)
#pragma unroll
        for (int j = 0; j < 4; ++j)
            ah[rt][j].u = ahi4[((size_t)(rt0 + rt) * 4 + j) * 64 + lane];

    unsigned int m1[8], m2[8];
#pragma unroll
    for (int s = 0; s < 8; ++s) { m1[s] = 0xFFFFFFFFu; m2[s] = 0xFFFFFFFFu; }

    const u32x4* p0 = bstr + (size_t)stripe * 8192 + lane;        // even tiles
    const u32x4* p1 = p0 + 256;                                   // odd tiles
    const u32x4* ipq = (const u32x4*)(ibt_t + stripe * 512 + colc * 32);
    i32x4 zc = (i32x4){0, 0, 0, 0};

    I16 bfA[4], bfB[4];
#pragma unroll
    for (int j = 0; j < 4; ++j) bfA[j].u = p0[j * 64];
    u32x4 ibC = ipq[0];                           // ibt for tiles 0..3
    u32x4 ibN = ibC;

    auto tilework = [&](const I16 (&bf)[4], unsigned int ibv) {
        i32x4 acc0, acc1;
        acc0 = __builtin_amdgcn_mfma_i32_16x16x64_i8(ah[0][0].i, bf[0].i, zc, 0, 0, 0);
        acc1 = __builtin_amdgcn_mfma_i32_16x16x64_i8(ah[1][0].i, bf[0].i, zc, 0, 0, 0);
#pragma unroll
        for (int j = 1; j < 4; ++j) {
            acc0 = __builtin_amdgcn_mfma_i32_16x16x64_i8(ah[0][j].i, bf[j].i, acc0, 0, 0, 0);
            acc1 = __builtin_amdgcn_mfma_i32_16x16x64_i8(ah[1][j].i, bf[j].i, acc1, 0, 0, 0);
        }
#pragma unroll
        for (int s = 0; s < 8; ++s) {
            unsigned int av = (unsigned int)((s < 4) ? acc0[s & 3] : acc1[s & 3]);
            unsigned int key;
            asm("v_lshl_add_u32 %0, %3, 6, %4\n\t"
                "v_med3_u32 %2, %0, %1, %2\n\t"
                "v_min_u32 %1, %1, %0"
                : "=&v"(key), "+v"(m1[s]), "+v"(m2[s])
                : "v"(av), "v"(ibv));
        }
    };

    for (int t = 0; t < 32; t += 4) {
#pragma unroll
        for (int j = 0; j < 4; ++j) bfB[j].u = p1[j * 64];        // tile t+1
        if (t + 4 < 32) ibN = ipq[(t >> 2) + 1];                  // next group
        tilework(bfA, ibC[0]);                                    // tile t
        p0 += 512;
#pragma unroll
        for (int j = 0; j < 4; ++j) bfA[j].u = p0[j * 64];        // tile t+2
        tilework(bfB, ibC[1]);                                    // tile t+1
        p1 += 512;
#pragma unroll
        for (int j = 0; j < 4; ++j) bfB[j].u = p1[j * 64];        // tile t+3
        tilework(bfA, ibC[2]);                                    // tile t+2
        if (t + 4 < 32) {
            p0 += 512;
#pragma unroll
            for (int j = 0; j < 4; ++j) bfA[j].u = p0[j * 64];    // tile t+4
        }
        tilework(bfB, ibC[3]);                                    // tile t+3
        p1 += 512;
        ibC = ibN;
    }

    // tail: per row-slot, top-3 of the 16 (m1,m2) across the 16 lanes sharing
    // the row (equal lane>>4; xor masks 1,2,4,8 stay in-group). UNCHANGED.
#pragma unroll
    for (int s = 0; s < 8; ++s) {
        int rt = s >> 2, r = s & 3;
        int row = (rt0 + rt) * 16 + (lane >> 4) * 4 + r;
        unsigned int v0 = m1[s], v1 = m2[s];
        int c0 = stripe * 512 + (int)(v0 & 63) * 16 + colc;
        int c1 = stripe * 512 + (int)(v1 & 63) * 16 + colc;
        int obase = (row * 16 + stripe) * 3;
#pragma unroll
        for (int k = 0; k < 3; ++k) {
            unsigned int bv; int bi;
            if (v1 < v0) { bv = v1; bi = c1; } else { bv = v0; bi = c0; }
#pragma unroll
            for (int mm = 1; mm < 16; mm <<= 1) {
                unsigned int ov = __shfl_xor(bv, mm, 64);
                int oi = __shfl_xor(bi, mm, 64);
                if (ov < bv || (ov == bv && oi < bi)) { bv = ov; bi = oi; }
            }
            if (colc == k) { cd[obase + k] = bv; ci[obase + k] = bi; }
            if (bi == c0) v0 = 0xFFFFFFFFu;
            if (bi == c1) v1 = 0xFFFFFFFFu;
        }
    }
}

// ---------------------------------------------------------------------------
// refine R16 (kept): exact semantics (f64 dot in identical accumulation
// order, rounded once; first-index ties; identical candidate order since the
// (d2, idx) comparison is a total order), singleton fast path + 3-deep
// software pipeline with static register stages.
// ---------------------------------------------------------------------------
__global__ __launch_bounds__(256)
void refine(const float* __restrict__ zt, const float* __restrict__ z2f,
            const float* __restrict__ cb, const float* __restrict__ c2,
            const unsigned int* __restrict__ cd, const int* __restrict__ ci,
            float* __restrict__ out, int* __restrict__ idxi) {
    int wid = threadIdx.x >> 6, lane = threadIdx.x & 63;
    int n = blockIdx.x * 4 + wid;
    float zq[4];
#pragma unroll
    for (int q = 0; q < 4; ++q) zq[q] = zt[(size_t)n * 256 + q * 64 + lane];
    float z2v = z2f[n];

    unsigned int kd = 0xFFFFFFFFu; int civ = 0;
    if (lane < 48) { kd = cd[n * 48 + lane]; civ = ci[n * 48 + lane]; }
    unsigned int rm = kd;
#pragma unroll
    for (int m = 32; m >= 1; m >>= 1) {
        unsigned int o = __shfl_xor(rm, m, 64);
        rm = o < rm ? o : rm;
    }
    bool active = (lane < 48) && ((kd >> 6) <= (rm >> 6) + WI);
    unsigned long long mask = __ballot(active);
    float bestd = FINF; int besti = 0x7fffffff;

    if ((mask & (mask - 1)) == 0ULL) {
        int k0 = __ffsll(mask) - 1;
        besti = __shfl(civ, k0, 64);
        if (lane == 0) { idxi[n] = besti; out[4194304 + n] = (float)besti; }
        return;
    }

    int kA = -1, kB = -1, kC = -1;
    int iA = 0, iB = 0, iC = 0;
    float a0 = 0, a1 = 0, a2 = 0, a3 = 0, cA = 0;
    float b0 = 0, b1 = 0, b2 = 0, b3 = 0, cB = 0;
    float e0 = 0, e1 = 0, e2 = 0, e3 = 0, cC = 0;

    if (mask) {
        kA = __ffsll(mask) - 1; mask &= mask - 1;
        iA = __shfl(civ, kA, 64);
        const float* cr = cb + (size_t)iA * 256;
        a0 = cr[lane]; a1 = cr[64 + lane]; a2 = cr[128 + lane]; a3 = cr[192 + lane];
        cA = c2[iA];
    }
    if (mask) {
        kB = __ffsll(mask) - 1; mask &= mask - 1;
        iB = __shfl(civ, kB, 64);
        const float* cr = cb + (size_t)iB * 256;
        b0 = cr[lane]; b1 = cr[64 + lane]; b2 = cr[128 + lane]; b3 = cr[192 + lane];
        cB = c2[iB];
    }
    if (mask) {
        kC = __ffsll(mask) - 1; mask &= mask - 1;
        iC = __shfl(civ, kC, 64);
        const float* cr = cb + (size_t)iC * 256;
        e0 = cr[lane]; e1 = cr[64 + lane]; e2 = cr[128 + lane]; e3 = cr[192 + lane];
        cC = c2[iC];
    }

    while (kA >= 0) {
        int kD = -1, iD = 0;
        float f0 = 0, f1 = 0, f2 = 0, f3 = 0, cD = 0;
        if (mask) {
            kD = __ffsll(mask) - 1; mask &= mask - 1;
            iD = __shfl(civ, kD, 64);
            const float* cr = cb + (size_t)iD * 256;
            f0 = cr[lane]; f1 = cr[64 + lane]; f2 = cr[128 + lane]; f3 = cr[192 + lane];
            cD = c2[iD];
        }
        double dot = 0.0;
        dot += (double)zq[0] * (double)a0;
        dot += (double)zq[1] * (double)a1;
        dot += (double)zq[2] * (double)a2;
        dot += (double)zq[3] * (double)a3;
#pragma unroll
        for (int m = 32; m >= 1; m >>= 1) dot += __shfl_xor(dot, m, 64);
        float Mf = (float)dot;
        float dd1 = z2v - 2.0f * Mf;
        float dd2 = dd1 + cA;
        if (dd2 < bestd || (dd2 == bestd && iA < besti)) { bestd = dd2; besti = iA; }
        kA = kB; iA = iB; a0 = b0; a1 = b1; a2 = b2; a3 = b3; cA = cB;
        kB = kC; iB = iC; b0 = e0; b1 = e1; b2 = e2; b3 = e3; cB = cC;
        kC = kD; iC = iD; e0 = f0; e1 = f1; e2 = f2; e3 = f3; cC = cD;
    }
    if (lane == 0) {
        idxi[n] = besti;
        out[4194304 + n] = (float)besti;
    }
}

// ---------------------------------------------------------------------------
// gather: z_q[b,d,h,w] = codebook[idx[b,h,w]][d], LDS transpose per (b,h).
// Vectorized (verified): cb loads float4, out stores float4 over w.
// ---------------------------------------------------------------------------
__global__ void gather_out(const float* __restrict__ cb,
                           const int* __restrict__ idxi,
                           float* __restrict__ out) {
    __shared__ float tile[32 * 260];
    __shared__ int sidx[32];
    int b = blockIdx.x >> 5, h = blockIdx.x & 31;
    int tid = threadIdx.x;
    if (tid < 32) sidx[tid] = idxi[(b * 32 + h) * 32 + tid];
    __syncthreads();
    for (int e = tid; e < 2048; e += 256) {       // 32 w x 64 d-quads
        int w = e >> 6, d4 = e & 63;
        float4 v = *reinterpret_cast<const float4*>(cb + (size_t)sidx[w] * 256 + d4 * 4);
        *reinterpret_cast<float4*>(&tile[w * 260 + d4 * 4]) = v;
    }
    __syncthreads();
    for (int e = tid; e < 2048; e += 256) {       // 256 d x 8 w-quads
        int d = e >> 3, w4 = e & 7;
        float4 v;
        v.x = tile[(w4 * 4 + 0) * 260 + d];
        v.y = tile[(w4 * 4 + 1) * 260 + d];
        v.z = tile[(w4 * 4 + 2) * 260 + d];
        v.w = tile[(w4 * 4 + 3) * 260 + d];
        *reinterpret_cast<float4*>(out + (((size_t)b * 256 + d) * 32 + h) * 32 + w4 * 4) = v;
    }
}

// ---------------------------------------------------------------------------
extern "C" void kernel_launch(void* const* d_in, const int* in_sizes, int n_in,
                              void* d_out, int out_size, void* d_ws, size_t ws_size,
                              hipStream_t stream) {
    const float* z  = (const float*)d_in[0];      // [16,256,32,32]
    const float* cb = (const float*)d_in[1];      // [8192,256]
    float* out = (float*)d_out;                   // z_q (4194304) + idx (16384)
    char* w = (char*)d_ws;
    // ws layout (bytes):
    //   ahi   0 .. 4,194,304 (4MB)  [idxi overlaid after vq_main]
    //   bstr  4,194,304 .. 6,291,456 (2MB)
    //   zt    6,291,456 .. 23,068,672 (16MB)
    //   c2 23,068,672 (+32K) | ibt_t 23,101,440 (+32K) | z2f 23,134,208 (+64K)
    //   cd 23,199,744 (+3M) | ci 26,345,472 (+3M) -> end 29,491,200
    u32x4* ahi  = (u32x4*)(w);
    u32x4* bstr = (u32x4*)(w + 4194304);
    float* zt   = (float*)(w + 6291456);
    float* c2   = (float*)(w + 23068672);
    unsigned int* ibt = (unsigned int*)(w + 23101440);
    float* z2f  = (float*)(w + 23134208);
    unsigned int* cd = (unsigned int*)(w + 23199744);
    int*   ci   = (int*)(w + 26345472);
    int*   idxi = (int*)(w);                      // overlays dead ahi region

    prep_all<<<1024, 256, 0, stream>>>(z, cb, ahi, zt, z2f, c2, ibt, bstr);
    vq_main<<<2048, 256, 0, stream>>>(ahi, bstr, ibt, cd, ci);
    refine<<<4096, 256, 0, stream>>>(zt, z2f, cb, c2, cd, ci, out, idxi);
    gather_out<<<512, 256, 0, stream>>>(cb, idxi, out);
}

// Round 12
// 155.052 us; speedup vs baseline: 1.0302x; 1.0302x over previous
//
#include <hip/hip_runtime.h>

typedef __attribute__((ext_vector_type(4))) unsigned int u32x4;
typedef __attribute__((ext_vector_type(4))) int i32x4;

union I16 { u32x4 u; i32x4 i; };

#define SA_INV   (127.0f / 12.0f)           // a = -2z, |a| <= 12 (z tail ~5.2)
#define SB_INV   (127.0f * 8192.0f)         // b in [-1/8192, 1/8192]
#define INV_SASB ((127.0 * 127.0 * 8192.0) / 12.0)   // 1/(sa*sb) ~ 1.101e7
#define WI       4500                        // refine window in int units (~4e-4)
#define FINF     3.4e38f

__device__ __forceinline__ int q8(float x, float s) {
    int q = (int)__builtin_rintf(x * s);
    return q < -127 ? -127 : (q > 127 ? 127 : q);
}

// ---------------------------------------------------------------------------
// prep_all R14 (verified best): float4 global accesses, all accumulation
// orders preserved -> outputs bit-identical to the scalar version. Standard
// ibt layout (R10's transposed layout regressed vq_main and is reverted).
// ---------------------------------------------------------------------------
__global__ __launch_bounds__(256)
void prep_all(const float* __restrict__ z, const float* __restrict__ cb,
              u32x4* __restrict__ ahi, float* __restrict__ zt,
              float* __restrict__ z2f, float* __restrict__ c2,
              unsigned int* __restrict__ ibt, u32x4* __restrict__ bstr) {
    __shared__ double pzbuf[32 * 9];              // doubles / pc floats
    __shared__ float tile[32 * 257];
    int tid = threadIdx.x;
    if (blockIdx.x < 512) {
        // ---- codebook path: one 16-code tile per block ----
        float* t16 = tile;                        // [16][257]
        float* pc = (float*)pzbuf;                // [16][17]
        int ct = blockIdx.x;
        int cl = tid >> 4, dseg = tid & 15;
        const float* src = cb + (size_t)(ct * 16 + cl) * 256 + dseg * 16;
        float s = 0.f;
#pragma unroll
        for (int q = 0; q < 4; ++q) {             // 4 x float4 = 16 floats, in order
            float4 v = *reinterpret_cast<const float4*>(src + q * 4);
            t16[cl * 257 + dseg * 16 + q * 4 + 0] = v.x; s += v.x * v.x;
            t16[cl * 257 + dseg * 16 + q * 4 + 1] = v.y; s += v.y * v.y;
            t16[cl * 257 + dseg * 16 + q * 4 + 2] = v.z; s += v.z * v.z;
            t16[cl * 257 + dseg * 16 + q * 4 + 3] = v.w; s += v.w * v.w;
        }
        pc[cl * 17 + dseg] = s;
        __syncthreads();
        if (tid < 16) {
            float t = 0.f;
#pragma unroll
            for (int i = 0; i < 16; ++i) t += pc[tid * 17 + i];
            int code = ct * 16 + tid;
            c2[code] = t;
            int ib = (int)__builtin_rintf(t * (float)INV_SASB);
            ibt[code] = (((unsigned int)(ib + 262144)) << 6) | (unsigned int)((code >> 4) & 31);
        }
        int l = tid & 63, j = tid >> 6;
        int code_l = l & 15, k0 = j * 64 + ((l >> 4) << 4);
        u32x4 v;
#pragma unroll
        for (int d = 0; d < 4; ++d) {
            unsigned int wv = 0;
#pragma unroll
            for (int bb = 0; bb < 4; ++bb) {
                int q = q8(t16[code_l * 257 + k0 + d * 4 + bb], SB_INV);
                wv |= ((unsigned int)(q & 255)) << (8 * bb);
            }
            v[d] = wv;
        }
        bstr[(size_t)(ct * 4 + j) * 64 + l] = v;
    } else {
        // ---- z path: one (b,h) pair per block ----
        int bh = blockIdx.x - 512;                // 0..511
        int b = bh >> 5, h = bh & 31;
        for (int e = tid; e < 2048; e += 256) {   // float4 over w
            int d = e >> 3, w4 = e & 7;
            float4 v = *reinterpret_cast<const float4*>(
                z + (((size_t)(b * 256 + d) * 32 + h) * 32) + w4 * 4);
            tile[(w4 * 4 + 0) * 257 + d] = v.x;
            tile[(w4 * 4 + 1) * 257 + d] = v.y;
            tile[(w4 * 4 + 2) * 257 + d] = v.z;
            tile[(w4 * 4 + 3) * 257 + d] = v.w;
        }
        __syncthreads();
        for (int e = tid; e < 2048; e += 256) {   // float4 over d
            int w = e >> 6, d4 = e & 63;
            float4 v;
            v.x = tile[w * 257 + d4 * 4 + 0];
            v.y = tile[w * 257 + d4 * 4 + 1];
            v.z = tile[w * 257 + d4 * 4 + 2];
            v.w = tile[w * 257 + d4 * 4 + 3];
            *reinterpret_cast<float4*>(zt + (size_t)(bh * 32 + w) * 256 + d4 * 4) = v;
        }
        {
            int w = tid >> 3, seg = tid & 7;
            double s = 0.0;
#pragma unroll
            for (int d = 0; d < 32; ++d) { double v = (double)tile[w * 257 + seg * 32 + d]; s += v * v; }
            pzbuf[w * 9 + seg] = s;
        }
        __syncthreads();
        if (tid < 32) {
            double s = 0.0;
#pragma unroll
            for (int seg = 0; seg < 8; ++seg) s += pzbuf[tid * 9 + seg];
            z2f[bh * 32 + tid] = (float)s;
        }
        for (int o = tid; o < 512; o += 256) {    // 2 row-tiles x 4 j x 64 lanes
            int l = o & 63, j = (o >> 6) & 3, tt = o >> 8;
            int wp = tt * 16 + (l & 15);
            int k0 = j * 64 + ((l >> 4) << 4);
            u32x4 v;
#pragma unroll
            for (int d = 0; d < 4; ++d) {
                unsigned int wv = 0;
#pragma unroll
                for (int bb = 0; bb < 4; ++bb) {
                    int q = q8(-2.0f * tile[wp * 257 + k0 + d * 4 + bb], SA_INV);
                    wv |= ((unsigned int)(q & 255)) << (8 * bb);
                }
                v[d] = wv;
            }
            ahi[(size_t)bh * 512 + o] = v;
        }
    }
}

// ---------------------------------------------------------------------------
// vq_main R15 (verified best, 67.6 us clean): XCD-locality remap + register
// double-buffer + med3 top-2 + top-3 tail, no LDS, no barriers, direct ibt
// loads, 2-tile step. Local optimum against: LDS staging (2 forms), wider
// tiles, setprio, ibt->LDS, ibt-transpose/4-tile step — all regressed or
// null across R0-R10.
// ---------------------------------------------------------------------------
__global__ __launch_bounds__(256)
void vq_main(const u32x4* __restrict__ ahi4, const u32x4* __restrict__ bstr,
             const unsigned int* __restrict__ ibt,
             unsigned int* __restrict__ cd, int* __restrict__ ci) {
    int tid = threadIdx.x;
    int wid = tid >> 6, lane = tid & 63;
    int b = blockIdx.x;
    int stripe = (b >> 3) & 15;                   // v
    int rg = (b & 7) * 16 + (b >> 7);             // x*16 + u, 0..127
    int colc = lane & 15;
    int rt0 = rg * 8 + wid * 2;                   // wave's 2 row-tiles (32 rows)

    I16 ah[2][4];
#pragma unroll
    for (int rt = 0; rt < 2; ++rt)
#pragma unroll
        for (int j = 0; j < 4; ++j)
            ah[rt][j].u = ahi4[((size_t)(rt0 + rt) * 4 + j) * 64 + lane];

    unsigned int m1[8], m2[8];
#pragma unroll
    for (int s = 0; s < 8; ++s) { m1[s] = 0xFFFFFFFFu; m2[s] = 0xFFFFFFFFu; }

    const u32x4* p0 = bstr + (size_t)stripe * 8192 + lane;        // even tiles
    const u32x4* p1 = p0 + 256;                                   // odd tiles
    const unsigned int* ip = ibt + stripe * 512 + colc;
    i32x4 zc = (i32x4){0, 0, 0, 0};

    I16 bfA[4], bfB[4];
    unsigned int ibA, ibB;
#pragma unroll
    for (int j = 0; j < 4; ++j) bfA[j].u = p0[j * 64];
    ibA = ip[0];

    auto tilework = [&](const I16 (&bf)[4], unsigned int ibv) {
        i32x4 acc0, acc1;
        acc0 = __builtin_amdgcn_mfma_i32_16x16x64_i8(ah[0][0].i, bf[0].i, zc, 0, 0, 0);
        acc1 = __builtin_amdgcn_mfma_i32_16x16x64_i8(ah[1][0].i, bf[0].i, zc, 0, 0, 0);
#pragma unroll
        for (int j = 1; j < 4; ++j) {
            acc0 = __builtin_amdgcn_mfma_i32_16x16x64_i8(ah[0][j].i, bf[j].i, acc0, 0, 0, 0);
            acc1 = __builtin_amdgcn_mfma_i32_16x16x64_i8(ah[1][j].i, bf[j].i, acc1, 0, 0, 0);
        }
#pragma unroll
        for (int s = 0; s < 8; ++s) {
            unsigned int av = (unsigned int)((s < 4) ? acc0[s & 3] : acc1[s & 3]);
            unsigned int key;
            asm("v_lshl_add_u32 %0, %3, 6, %4\n\t"
                "v_med3_u32 %2, %0, %1, %2\n\t"
                "v_min_u32 %1, %1, %0"
                : "=&v"(key), "+v"(m1[s]), "+v"(m2[s])
                : "v"(av), "v"(ibv));
        }
    };

    for (int t = 0; t < 32; t += 2) {
#pragma unroll
        for (int j = 0; j < 4; ++j) bfB[j].u = p1[j * 64];        // prefetch t+1
        ibB = ip[(t + 1) * 16];
        tilework(bfA, ibA);
        if (t + 2 < 32) {
            p0 += 512;
#pragma unroll
            for (int j = 0; j < 4; ++j) bfA[j].u = p0[j * 64];    // prefetch t+2
            ibA = ip[(t + 2) * 16];
        }
        tilework(bfB, ibB);
        p1 += 512;
    }

    // tail: per row-slot, top-3 of the 16 (m1,m2) across the 16 lanes sharing
    // the row (equal lane>>4; xor masks 1,2,4,8 stay in-group). UNCHANGED.
#pragma unroll
    for (int s = 0; s < 8; ++s) {
        int rt = s >> 2, r = s & 3;
        int row = (rt0 + rt) * 16 + (lane >> 4) * 4 + r;
        unsigned int v0 = m1[s], v1 = m2[s];
        int c0 = stripe * 512 + (int)(v0 & 63) * 16 + colc;
        int c1 = stripe * 512 + (int)(v1 & 63) * 16 + colc;
        int obase = (row * 16 + stripe) * 3;
#pragma unroll
        for (int k = 0; k < 3; ++k) {
            unsigned int bv; int bi;
            if (v1 < v0) { bv = v1; bi = c1; } else { bv = v0; bi = c0; }
#pragma unroll
            for (int mm = 1; mm < 16; mm <<= 1) {
                unsigned int ov = __shfl_xor(bv, mm, 64);
                int oi = __shfl_xor(bi, mm, 64);
                if (ov < bv || (ov == bv && oi < bi)) { bv = ov; bi = oi; }
            }
            if (colc == k) { cd[obase + k] = bv; ci[obase + k] = bi; }
            if (bi == c0) v0 = 0xFFFFFFFFu;
            if (bi == c1) v1 = 0xFFFFFFFFu;
        }
    }
}

// ---------------------------------------------------------------------------
// refine R16 (verified): exact semantics (f64 dot in identical accumulation
// order, rounded once; first-index ties), singleton fast path + 3-deep
// software pipeline with static register stages.
// ---------------------------------------------------------------------------
__global__ __launch_bounds__(256)
void refine(const float* __restrict__ zt, const float* __restrict__ z2f,
            const float* __restrict__ cb, const float* __restrict__ c2,
            const unsigned int* __restrict__ cd, const int* __restrict__ ci,
            float* __restrict__ out, int* __restrict__ idxi) {
    int wid = threadIdx.x >> 6, lane = threadIdx.x & 63;
    int n = blockIdx.x * 4 + wid;
    float zq[4];
#pragma unroll
    for (int q = 0; q < 4; ++q) zq[q] = zt[(size_t)n * 256 + q * 64 + lane];
    float z2v = z2f[n];

    unsigned int kd = 0xFFFFFFFFu; int civ = 0;
    if (lane < 48) { kd = cd[n * 48 + lane]; civ = ci[n * 48 + lane]; }
    unsigned int rm = kd;
#pragma unroll
    for (int m = 32; m >= 1; m >>= 1) {
        unsigned int o = __shfl_xor(rm, m, 64);
        rm = o < rm ? o : rm;
    }
    bool active = (lane < 48) && ((kd >> 6) <= (rm >> 6) + WI);
    unsigned long long mask = __ballot(active);
    float bestd = FINF; int besti = 0x7fffffff;

    if ((mask & (mask - 1)) == 0ULL) {
        int k0 = __ffsll(mask) - 1;
        besti = __shfl(civ, k0, 64);
        if (lane == 0) { idxi[n] = besti; out[4194304 + n] = (float)besti; }
        return;
    }

    int kA = -1, kB = -1, kC = -1;
    int iA = 0, iB = 0, iC = 0;
    float a0 = 0, a1 = 0, a2 = 0, a3 = 0, cA = 0;
    float b0 = 0, b1 = 0, b2 = 0, b3 = 0, cB = 0;
    float e0 = 0, e1 = 0, e2 = 0, e3 = 0, cC = 0;

    if (mask) {
        kA = __ffsll(mask) - 1; mask &= mask - 1;
        iA = __shfl(civ, kA, 64);
        const float* cr = cb + (size_t)iA * 256;
        a0 = cr[lane]; a1 = cr[64 + lane]; a2 = cr[128 + lane]; a3 = cr[192 + lane];
        cA = c2[iA];
    }
    if (mask) {
        kB = __ffsll(mask) - 1; mask &= mask - 1;
        iB = __shfl(civ, kB, 64);
        const float* cr = cb + (size_t)iB * 256;
        b0 = cr[lane]; b1 = cr[64 + lane]; b2 = cr[128 + lane]; b3 = cr[192 + lane];
        cB = c2[iB];
    }
    if (mask) {
        kC = __ffsll(mask) - 1; mask &= mask - 1;
        iC = __shfl(civ, kC, 64);
        const float* cr = cb + (size_t)iC * 256;
        e0 = cr[lane]; e1 = cr[64 + lane]; e2 = cr[128 + lane]; e3 = cr[192 + lane];
        cC = c2[iC];
    }

    while (kA >= 0) {
        int kD = -1, iD = 0;
        float f0 = 0, f1 = 0, f2 = 0, f3 = 0, cD = 0;
        if (mask) {
            kD = __ffsll(mask) - 1; mask &= mask - 1;
            iD = __shfl(civ, kD, 64);
            const float* cr = cb + (size_t)iD * 256;
            f0 = cr[lane]; f1 = cr[64 + lane]; f2 = cr[128 + lane]; f3 = cr[192 + lane];
            cD = c2[iD];
        }
        double dot = 0.0;
        dot += (double)zq[0] * (double)a0;
        dot += (double)zq[1] * (double)a1;
        dot += (double)zq[2] * (double)a2;
        dot += (double)zq[3] * (double)a3;
#pragma unroll
        for (int m = 32; m >= 1; m >>= 1) dot += __shfl_xor(dot, m, 64);
        float Mf = (float)dot;
        float dd1 = z2v - 2.0f * Mf;
        float dd2 = dd1 + cA;
        if (dd2 < bestd || (dd2 == bestd && iA < besti)) { bestd = dd2; besti = iA; }
        kA = kB; iA = iB; a0 = b0; a1 = b1; a2 = b2; a3 = b3; cA = cB;
        kB = kC; iB = iC; b0 = e0; b1 = e1; b2 = e2; b3 = e3; cB = cC;
        kC = kD; iC = iD; e0 = f0; e1 = f1; e2 = f2; e3 = f3; cC = cD;
    }
    if (lane == 0) {
        idxi[n] = besti;
        out[4194304 + n] = (float)besti;
    }
}

// ---------------------------------------------------------------------------
// gather: z_q[b,d,h,w] = codebook[idx[b,h,w]][d], LDS transpose per (b,h).
// Vectorized (verified): cb loads float4, out stores float4 over w.
// ---------------------------------------------------------------------------
__global__ void gather_out(const float* __restrict__ cb,
                           const int* __restrict__ idxi,
                           float* __restrict__ out) {
    __shared__ float tile[32 * 260];
    __shared__ int sidx[32];
    int b = blockIdx.x >> 5, h = blockIdx.x & 31;
    int tid = threadIdx.x;
    if (tid < 32) sidx[tid] = idxi[(b * 32 + h) * 32 + tid];
    __syncthreads();
    for (int e = tid; e < 2048; e += 256) {       // 32 w x 64 d-quads
        int w = e >> 6, d4 = e & 63;
        float4 v = *reinterpret_cast<const float4*>(cb + (size_t)sidx[w] * 256 + d4 * 4);
        *reinterpret_cast<float4*>(&tile[w * 260 + d4 * 4]) = v;
    }
    __syncthreads();
    for (int e = tid; e < 2048; e += 256) {       // 256 d x 8 w-quads
        int d = e >> 3, w4 = e & 7;
        float4 v;
        v.x = tile[(w4 * 4 + 0) * 260 + d];
        v.y = tile[(w4 * 4 + 1) * 260 + d];
        v.z = tile[(w4 * 4 + 2) * 260 + d];
        v.w = tile[(w4 * 4 + 3) * 260 + d];
        *reinterpret_cast<float4*>(out + (((size_t)b * 256 + d) * 32 + h) * 32 + w4 * 4) = v;
    }
}

// ---------------------------------------------------------------------------
extern "C" void kernel_launch(void* const* d_in, const int* in_sizes, int n_in,
                              void* d_out, int out_size, void* d_ws, size_t ws_size,
                              hipStream_t stream) {
    const float* z  = (const float*)d_in[0];      // [16,256,32,32]
    const float* cb = (const float*)d_in[1];      // [8192,256]
    float* out = (float*)d_out;                   // z_q (4194304) + idx (16384)
    char* w = (char*)d_ws;
    // ws layout (bytes):
    //   ahi   0 .. 4,194,304 (4MB)  [idxi overlaid after vq_main]
    //   bstr  4,194,304 .. 6,291,456 (2MB)
    //   zt    6,291,456 .. 23,068,672 (16MB)
    //   c2 23,068,672 (+32K) | ibt 23,101,440 (+32K) | z2f 23,134,208 (+64K)
    //   cd 23,199,744 (+3M) | ci 26,345,472 (+3M) -> end 29,491,200
    u32x4* ahi  = (u32x4*)(w);
    u32x4* bstr = (u32x4*)(w + 4194304);
    float* zt   = (float*)(w + 6291456);
    float* c2   = (float*)(w + 23068672);
    unsigned int* ibt = (unsigned int*)(w + 23101440);
    float* z2f  = (float*)(w + 23134208);
    unsigned int* cd = (unsigned int*)(w + 23199744);
    int*   ci   = (int*)(w + 26345472);
    int*   idxi = (int*)(w);                      // overlays dead ahi region

    prep_all<<<1024, 256, 0, stream>>>(z, cb, ahi, zt, z2f, c2, ibt, bstr);
    vq_main<<<2048, 256, 0, stream>>>(ahi, bstr, ibt, cd, ci);
    refine<<<4096, 256, 0, stream>>>(zt, z2f, cb, c2, cd, ci, out, idxi);
    gather_out<<<512, 256, 0, stream>>>(cb, idxi, out);
}